// Round 1
// baseline (21.712 us; speedup 1.0000x reference)
//
#include <hip/hip_runtime.h>
#include <math.h>

// Algebraic reduction of the reference:
//   x_pkg2 == 0  =>  conv2 output h2[t][i,:] == b2[t]  (attention * zeros)
//   =>  s[t] = softmax(b2[t] @ Ws[t])  (one [C] vector, identical for all N rows)
//   =>  cross_t = E_t / C
//       sq_t    = (N^2 / C) * ||s_t||^2
//       link_t  = sqrt(max(E_t - 2 E_t/C + sq_t, 0)) / N^2
//       ent     = ( sum_t [-sum_c s_t log(s_t+1e-15)] + (-log(1/C + 1e-15)) ) / 7
// Only b2 (d_in[20]) and Ws (d_in[21]) plus edge counts / N are live inputs.

#define HDIM 128
#define NCLUST 64
#define NTYPES 6

__global__ __launch_bounds__(64) void MaskedHeteroGAT_23106924052984_kernel(
    const float* __restrict__ b2,   // [6][128]
    const float* __restrict__ Ws,   // [6][128][64]
    float* __restrict__ out,        // [1]
    int n_nodes,
    int e0, int e1, int e2, int e3, int e4, int e5)
{
    const int c = threadIdx.x;  // one lane per cluster, 0..63
    const int ne[NTYPES] = {e0, e1, e2, e3, e4, e5};

    const float n2 = (float)n_nodes * (float)n_nodes;
    float link = 0.0f;
    float entsum = 0.0f;

    for (int t = 0; t < NTYPES; ++t) {
        // z[c] = b2[t] . Ws[t][:, c]
        const float* bt = b2 + t * HDIM;
        const float* wt = Ws + (size_t)t * HDIM * NCLUST + c;
        float z = 0.0f;
        #pragma unroll 8
        for (int k = 0; k < HDIM; ++k) {
            z = fmaf(bt[k], wt[(size_t)k * NCLUST], z);
        }

        // softmax across the 64-lane wave (lane == cluster index)
        float m = z;
        #pragma unroll
        for (int off = 1; off < 64; off <<= 1)
            m = fmaxf(m, __shfl_xor(m, off, 64));
        float p = expf(z - m);
        float d = p;
        #pragma unroll
        for (int off = 1; off < 64; off <<= 1)
            d += __shfl_xor(d, off, 64);
        float s = p / d;

        // sum of squares and entropy terms, reduced across the wave
        float v0 = s * s;
        float v1 = -s * logf(s + 1e-15f);
        #pragma unroll
        for (int off = 1; off < 64; off <<= 1) {
            v0 += __shfl_xor(v0, off, 64);
            v1 += __shfl_xor(v1, off, 64);
        }

        const float nef = (float)ne[t];
        const float inside = nef - 2.0f * nef / (float)NCLUST
                           + (n2 / (float)NCLUST) * v0;
        link += sqrtf(fmaxf(inside, 0.0f)) / n2;
        entsum += v1;
    }

    if (c == 0) {
        const float ent_pkg = -logf(1.0f / (float)NCLUST + 1e-15f);
        out[0] = link + (entsum + ent_pkg) / 7.0f;
    }
}

extern "C" void kernel_launch(void* const* d_in, const int* in_sizes, int n_in,
                              void* d_out, int out_size, void* d_ws, size_t ws_size,
                              hipStream_t stream) {
    // setup_inputs() dict order:
    //  0..6  : x_pkg, x_path, x_dns, x_cmd, x_ip, x_port, x_host   (dead)
    //  7..12 : ei_path..ei_host  (only their COUNTS are live)
    //  13..16: Wl1, Wr1, a1, b1   (dead)
    //  17..19: Wl2, Wr2, a2       (dead)
    //  20    : b2  [6*128]
    //  21    : Ws  [6*128*64]
    const float* b2 = (const float*)d_in[20];
    const float* Ws = (const float*)d_in[21];
    float* out = (float*)d_out;

    const int n_nodes = in_sizes[0] / HDIM;
    int e[NTYPES];
    for (int t = 0; t < NTYPES; ++t) e[t] = in_sizes[7 + t] / 2;

    MaskedHeteroGAT_23106924052984_kernel<<<1, 64, 0, stream>>>(
        b2, Ws, out, n_nodes, e[0], e[1], e[2], e[3], e[4], e[5]);
}

// Round 2
// 9.846 us; speedup vs baseline: 2.2052x; 2.2052x over previous
//
#include <hip/hip_runtime.h>
#include <math.h>

// Algebraic reduction of the reference (verified exact, round 1, absmax 0.0):
//   x_pkg2 == 0  =>  conv2 output h2[t][i,:] == b2[t]  (attention * zeros)
//   =>  s[t] = softmax(b2[t] @ Ws[t])  (one [C] vector, identical for all N rows)
//   =>  cross_t = E_t / C
//       sq_t    = (N^2 / C) * ||s_t||^2
//       link_t  = sqrt(max(E_t - 2 E_t/C + sq_t, 0)) / N^2
//       ent     = ( sum_t [-sum_c s_t log(s_t+1e-15)] + (-log(1/C + 1e-15)) ) / 7
// Only b2 (d_in[20]) and Ws (d_in[21]) plus edge counts / N are live inputs.
//
// Round 2: latency optimization. One block, 6 waves — wave t owns type t
// (was: 1 wave serial over 6 types). All 128 column loads issued up front
// into registers (static indices -> VGPRs, not scratch), 4-way split
// accumulator. Expect ~launch-floor timing.

#define HDIM 128
#define NCLUST 64
#define NTYPES 6

__global__ __launch_bounds__(NTYPES * 64) void MaskedHeteroGAT_23106924052984_kernel(
    const float* __restrict__ b2,   // [6][128]
    const float* __restrict__ Ws,   // [6][128][64]
    float* __restrict__ out,        // [1]
    int n_nodes,
    int e0, int e1, int e2, int e3, int e4, int e5)
{
    const int t = threadIdx.x >> 6;   // wave id == edge type
    const int c = threadIdx.x & 63;   // lane == cluster index

    __shared__ float link_s[NTYPES];
    __shared__ float ent_s[NTYPES];

    const int ne[NTYPES] = {e0, e1, e2, e3, e4, e5};
    const float n2 = (float)n_nodes * (float)n_nodes;

    const float* bt = b2 + t * HDIM;                       // wave-uniform
    const float* wt = Ws + (size_t)t * HDIM * NCLUST + c;  // lane-strided column

    // Issue ALL column loads before any use: one memory-latency round trip.
    float w[HDIM];
    #pragma unroll
    for (int k = 0; k < HDIM; ++k)
        w[k] = wt[(size_t)k * NCLUST];

    // z[c] = b2[t] . Ws[t][:, c], 4-way split accumulator
    float z0 = 0.0f, z1 = 0.0f, z2 = 0.0f, z3 = 0.0f;
    #pragma unroll
    for (int k = 0; k < HDIM; k += 4) {
        z0 = fmaf(bt[k + 0], w[k + 0], z0);
        z1 = fmaf(bt[k + 1], w[k + 1], z1);
        z2 = fmaf(bt[k + 2], w[k + 2], z2);
        z3 = fmaf(bt[k + 3], w[k + 3], z3);
    }
    float z = (z0 + z1) + (z2 + z3);

    // softmax across the 64-lane wave (lane == cluster)
    float m = z;
    #pragma unroll
    for (int off = 1; off < 64; off <<= 1)
        m = fmaxf(m, __shfl_xor(m, off, 64));
    float p = expf(z - m);
    float d = p;
    #pragma unroll
    for (int off = 1; off < 64; off <<= 1)
        d += __shfl_xor(d, off, 64);
    float s = p / d;

    // sum of squares and entropy, reduced across the wave
    float v0 = s * s;
    float v1 = -s * logf(s + 1e-15f);
    #pragma unroll
    for (int off = 1; off < 64; off <<= 1) {
        v0 += __shfl_xor(v0, off, 64);
        v1 += __shfl_xor(v1, off, 64);
    }

    if (c == 0) {
        const float nef = (float)ne[t];
        const float inside = nef - 2.0f * nef / (float)NCLUST
                           + (n2 / (float)NCLUST) * v0;
        link_s[t] = sqrtf(fmaxf(inside, 0.0f)) / n2;
        ent_s[t]  = v1;
    }
    __syncthreads();

    if (threadIdx.x == 0) {
        float link = 0.0f, entsum = 0.0f;
        #pragma unroll
        for (int i = 0; i < NTYPES; ++i) {
            link   += link_s[i];
            entsum += ent_s[i];
        }
        const float ent_pkg = -logf(1.0f / (float)NCLUST + 1e-15f);
        out[0] = link + (entsum + ent_pkg) / 7.0f;
    }
}

extern "C" void kernel_launch(void* const* d_in, const int* in_sizes, int n_in,
                              void* d_out, int out_size, void* d_ws, size_t ws_size,
                              hipStream_t stream) {
    // setup_inputs() dict order:
    //  0..6  : x_pkg, x_path, x_dns, x_cmd, x_ip, x_port, x_host   (dead)
    //  7..12 : ei_path..ei_host  (only their COUNTS are live)
    //  13..19: Wl1, Wr1, a1, b1, Wl2, Wr2, a2                      (dead)
    //  20    : b2  [6*128]
    //  21    : Ws  [6*128*64]
    const float* b2 = (const float*)d_in[20];
    const float* Ws = (const float*)d_in[21];
    float* out = (float*)d_out;

    const int n_nodes = in_sizes[0] / HDIM;
    int e[NTYPES];
    for (int t = 0; t < NTYPES; ++t) e[t] = in_sizes[7 + t] / 2;

    MaskedHeteroGAT_23106924052984_kernel<<<1, NTYPES * 64, 0, stream>>>(
        b2, Ws, out, n_nodes, e[0], e[1], e[2], e[3], e[4], e[5]);
}